// Round 1
// baseline (440.256 us; speedup 1.0000x reference)
//
#include <hip/hip_runtime.h>
#include <math.h>

// Problem constants (from reference): B=8, T=4096, D=2048, W=4, fp32 in/out.
#define CB 8
#define CT 4096
#define CD 2048
#define CW 4
#define TC 64          // t-steps per thread (halo overhead = 3/64 ~ 5%)
#define D4 (CD / 4)    // 512 float4 lanes across D

__global__ __launch_bounds__(256) void conv_silu_kernel(
    const float4* __restrict__ x,      // [B, T, D4]
    const float4* __restrict__ w,      // [W, D4]
    float4* __restrict__ out)          // [B, T, D4]
{
    const int d4 = blockIdx.x * blockDim.x + threadIdx.x;  // 0..D4-1
    const int t0 = blockIdx.y * TC;
    const int b  = blockIdx.z;

    const float4* xb = x   + (size_t)b * CT * D4;
    float4*       ob = out + (size_t)b * CT * D4;

    // Per-channel weights (4 float4 = 16 fp32), read once, L2-cached.
    const float4 w0 = w[0 * D4 + d4];
    const float4 w1 = w[1 * D4 + d4];
    const float4 w2 = w[2 * D4 + d4];
    const float4 w3 = w[3 * D4 + d4];

    // Rolling window x[t-3], x[t-2], x[t-1]. t0 is a multiple of TC (>=4),
    // so only the t0==0 chunk touches the causal zero-pad.
    float4 xm3 = make_float4(0.f, 0.f, 0.f, 0.f);
    float4 xm2 = xm3;
    float4 xm1 = xm3;
    if (t0 > 0) {
        xm3 = xb[(size_t)(t0 - 3) * D4 + d4];
        xm2 = xb[(size_t)(t0 - 2) * D4 + d4];
        xm1 = xb[(size_t)(t0 - 1) * D4 + d4];
    }

#pragma unroll 4
    for (int t = t0; t < t0 + TC; ++t) {
        const float4 xt = xb[(size_t)t * D4 + d4];

        float4 a;
        a.x = w0.x * xm3.x + w1.x * xm2.x + w2.x * xm1.x + w3.x * xt.x;
        a.y = w0.y * xm3.y + w1.y * xm2.y + w2.y * xm1.y + w3.y * xt.y;
        a.z = w0.z * xm3.z + w1.z * xm2.z + w2.z * xm1.z + w3.z * xt.z;
        a.w = w0.w * xm3.w + w1.w * xm2.w + w2.w * xm1.w + w3.w * xt.w;

        // SiLU: v * sigmoid(v) = v / (1 + exp(-v))
        a.x = a.x / (1.f + __expf(-a.x));
        a.y = a.y / (1.f + __expf(-a.y));
        a.z = a.z / (1.f + __expf(-a.z));
        a.w = a.w / (1.f + __expf(-a.w));

        ob[(size_t)t * D4 + d4] = a;

        xm3 = xm2;
        xm2 = xm1;
        xm1 = xt;
    }
}

extern "C" void kernel_launch(void* const* d_in, const int* in_sizes, int n_in,
                              void* d_out, int out_size, void* d_ws, size_t ws_size,
                              hipStream_t stream) {
    const float4* x = (const float4*)d_in[0];   // [B,T,D] fp32
    const float4* w = (const float4*)d_in[1];   // [W,1,D] fp32
    float4* out = (float4*)d_out;               // [B,T,D] fp32

    dim3 block(256);
    dim3 grid(D4 / 256, CT / TC, CB);           // (2, 64, 8) = 1024 blocks
    conv_silu_kernel<<<grid, block, 0, stream>>>(x, w, out);
}